// Round 9
// baseline (262.364 us; speedup 1.0000x reference)
//
#include <hip/hip_runtime.h>
#include <hip/hip_bf16.h>

typedef __hip_bfloat16 bf16;
typedef __attribute__((ext_vector_type(8))) short bf16x8;
typedef __attribute__((ext_vector_type(4))) float floatx4;
typedef unsigned short ushort;
typedef unsigned int uint;

#define ROWS 32768
#define KX 96          // padded d_ext (70 -> 96)

#define MFMA(a, b, c) __builtin_amdgcn_mfma_f32_16x16x32_bf16(a, b, c, 0, 0, 0)
#define GL_LDS(gp, lp) __builtin_amdgcn_global_load_lds( \
    (const __attribute__((address_space(1))) unsigned int*)(gp), \
    (__attribute__((address_space(3))) unsigned int*)(lp), 16, 0, 0)

__device__ __forceinline__ ushort f2bf(float f) {
  union { float f; unsigned int i; } u; u.f = f;
  return (ushort)((u.i + 0x7fffu + ((u.i >> 16) & 1u)) >> 16);   // RNE
}

// ---------------- prep: xe (32768 x 96 bf16) + biases ----------------
__global__ void prep_misc(const float* __restrict__ x, const float* __restrict__ pos,
    const float* __restrict__ bk1, const float* __restrict__ bq1, const float* __restrict__ bv1,
    const float* __restrict__ bk2, const float* __restrict__ bq2, const float* __restrict__ bv2,
    bf16* __restrict__ xe, float* __restrict__ b1, float* __restrict__ b2)
{
  int idx = blockIdx.x * 256 + threadIdx.x;
  if (idx < ROWS * KX) {
    int r = idx / KX, col = idx - r * KX;
    float v = 0.f;
    if (col < 64)      v = x[r * 64 + col];
    else if (col < 70) v = pos[(r & 15) * 6 + (col - 64)];
    xe[idx] = __float2bfloat16(v);
  } else if (idx < ROWS * KX + 3072) {
    int i = idx - ROWS * KX;
    if (i < 1536) {
      int z = i >> 9, nl = i & 511;
      const float* s = (z == 0) ? bk1 : (z == 1) ? bq1 : bv1;
      b1[i] = s[nl];
    } else {
      int j = i - 1536;
      int z = j >> 9, nl = j & 511;
      const float* s = (z == 0) ? bk2 : (z == 1) ? bq2 : bv2;
      b2[j] = s[nl];
    }
  }
}

// ---------------- prep: tiled transpose W1 (70x512 -> [z*512+n]x96), W2 (512x512 -> n,k) ----------------
__global__ __launch_bounds__(256) void prep_wt(
    const float* __restrict__ Wk_h, const float* __restrict__ Wq_h, const float* __restrict__ Wv_h,
    const float* __restrict__ Wk_o, const float* __restrict__ Wq_o, const float* __restrict__ Wv_o,
    bf16* __restrict__ w1t, bf16* __restrict__ w2t)
{
  __shared__ float tile[32][33];
  const int bid = blockIdx.x;
  const int c = threadIdx.x & 31, r0 = threadIdx.x >> 5;
  if (bid < 768) {            // W2: z x nt(16) x kt(16)
    const int z = bid >> 8, rem = bid & 255;
    const int nt = rem >> 4, kt = rem & 15;
    const float* src = (z == 0) ? Wk_o : (z == 1) ? Wq_o : Wv_o;
    #pragma unroll
    for (int rr = 0; rr < 4; ++rr) {
      int r = r0 + rr * 8;
      tile[r][c] = src[(kt * 32 + r) * 512 + nt * 32 + c];
    }
    __syncthreads();
    #pragma unroll
    for (int rr = 0; rr < 4; ++rr) {
      int r = r0 + rr * 8;
      w2t[((long)z * 512 + nt * 32 + r) * 512 + kt * 32 + c] = __float2bfloat16(tile[c][r]);
    }
  } else {                    // W1: z(3) x kt(3) x nt(16)
    const int b2i = bid - 768;
    const int z = b2i / 48, rem = b2i - z * 48;
    const int kt = rem >> 4, nt = rem & 15;
    const float* src = (z == 0) ? Wk_h : (z == 1) ? Wq_h : Wv_h;
    #pragma unroll
    for (int rr = 0; rr < 4; ++rr) {
      int r = r0 + rr * 8;
      int k = kt * 32 + r;
      tile[r][c] = (k < 70) ? src[k * 512 + nt * 32 + c] : 0.f;
    }
    __syncthreads();
    #pragma unroll
    for (int rr = 0; rr < 4; ++rr) {
      int r = r0 + rr * 8;
      w1t[((long)z * 512 + nt * 32 + r) * KX + kt * 32 + c] = __float2bfloat16(tile[c][r]);
    }
  }
}

// ---------------- GEMM1: barrier-free, LDS-free. A-frags in regs, B from L2 ----------------
// grid (512, 6): 64 rows x 256 cols per block; 4 waves, wave w -> rows [16w,16w+16).
__global__ __launch_bounds__(256, 3) void gemm1_reg(
    const bf16* __restrict__ xe, const bf16* __restrict__ w1t,
    const float* __restrict__ bias, bf16* __restrict__ hid)
{
  const int tid = threadIdx.x, w = tid >> 6, lane = tid & 63;
  const int r0 = blockIdx.x * 64;
  const int bn = blockIdx.y * 256;
  const int rowl = lane & 15, kg = (lane >> 4) * 8;

  bf16x8 a0, a1, a2;
  {
    const bf16* xp = xe + (long)(r0 + 16 * w + rowl) * KX + kg;
    a0 = *(const bf16x8*)xp;
    a1 = *(const bf16x8*)(xp + 32);
    a2 = *(const bf16x8*)(xp + 64);
  }

  floatx4 acc[16];
  #pragma unroll
  for (int nt = 0; nt < 16; ++nt) acc[nt] = (floatx4){0.f, 0.f, 0.f, 0.f};

  const bf16* wp = w1t + (long)(bn + rowl) * KX + kg;
  #pragma unroll
  for (int nt = 0; nt < 16; ++nt) {
    const bf16* bp = wp + (long)nt * 16 * KX;
    bf16x8 b0 = *(const bf16x8*)bp;
    bf16x8 b1 = *(const bf16x8*)(bp + 32);
    bf16x8 b2 = *(const bf16x8*)(bp + 64);
    acc[nt] = MFMA(a0, b0, acc[nt]);
    acc[nt] = MFMA(a1, b1, acc[nt]);
    acc[nt] = MFMA(a2, b2, acc[nt]);
  }

  // epilogue: bias + silu + packed u32 stores (even lanes store col pairs)
  const int m0 = r0 + 16 * w + (lane >> 4) * 4;
  #pragma unroll
  for (int nt = 0; nt < 16; ++nt) {
    const int col = bn + nt * 16 + rowl;
    const float bv = bias[col];
    #pragma unroll
    for (int r = 0; r < 4; ++r) {
      float v = acc[nt][r] + bv;
      v = v / (1.f + __expf(-v));            // silu
      float vp = __shfl_xor(v, 1);
      if (!(rowl & 1)) {
        uint pk = (uint)f2bf(v) | ((uint)f2bf(vp) << 16);
        *(uint*)(hid + (long)(m0 + r) * 1536 + col) = pk;
      }
    }
  }
}

// ---------------- GEMM2: m97 128x128 + 2-phase double-buffer (counted overlap) ----------------
// grid (256, 12): y -> (z = y>>2, nb = y&3). K=512 (16 K-steps).
// Epilogue: z<2 -> kqv rows; z==2 -> vT[b][col][j] packed (for attn PV).
__global__ __launch_bounds__(256) void mlp_gemm2(
    const bf16* __restrict__ A,            // hid, lda = 1536 (col offset z*512)
    const bf16* __restrict__ Bt,           // w2t [1536][512]
    const float* __restrict__ bias,        // flat 1536
    bf16* __restrict__ C)                  // kqv base (k | q | vT)
{
  __shared__ __align__(16) bf16 As[2][128 * 32];
  __shared__ __align__(16) bf16 Bs[2][128 * 32];
  const int tid  = threadIdx.x;
  const int wave = tid >> 6, lane = tid & 63;
  const int z  = blockIdx.y >> 2;
  const int bn = (blockIdx.y & 3) * 128;         // within z
  const int bm = blockIdx.x * 128;
  const int bnf = z * 512 + bn;                  // flat n
  const bf16* Ap  = A + z * 512;
  const bf16* Btp = Bt + (long)z * 512 * 512;
  const int wm = (wave >> 1) * 64;
  const int wn = (wave & 1) * 64;
  const int arow = lane >> 2;
  const int acol = (lane & 3) * 8;

#define STAGE2(buf, t) do {                                                   \
    const int k0_ = (t) * 32;                                                 \
    _Pragma("unroll")                                                         \
    for (int ch = 0; ch < 2; ++ch) {                                          \
      const int rb = wave * 32 + ch * 16;                                     \
      GL_LDS(Ap  + (long)(bm + rb + arow) * 1536 + k0_ + acol, As[buf] + rb * 32); \
      GL_LDS(Btp + (long)(bn + rb + arow) * 512  + k0_ + acol, Bs[buf] + rb * 32); \
    } } while (0)

  STAGE2(0, 0);
  asm volatile("s_waitcnt vmcnt(0)" ::: "memory");
  __syncthreads();

  floatx4 acc[4][4] = {};
  int cur = 0;
  for (int t = 0; t < 16; ++t) {
    if (t + 1 < 16) STAGE2(cur ^ 1, t + 1);      // issue next tile; stays in flight over compute
    bf16x8 af[4], bfr[4];
    #pragma unroll
    for (int mi = 0; mi < 4; ++mi)
      af[mi] = *(const bf16x8*)(As[cur] + (wm + mi * 16 + (lane & 15)) * 32 + (lane >> 4) * 8);
    #pragma unroll
    for (int ni = 0; ni < 4; ++ni)
      bfr[ni] = *(const bf16x8*)(Bs[cur] + (wn + ni * 16 + (lane & 15)) * 32 + (lane >> 4) * 8);
    #pragma unroll
    for (int mi = 0; mi < 4; ++mi)
      #pragma unroll
      for (int ni = 0; ni < 4; ++ni)
        acc[mi][ni] = MFMA(af[mi], bfr[ni], acc[mi][ni]);
    if (t + 1 < 16) {
      asm volatile("s_waitcnt vmcnt(0)" ::: "memory");   // next tile landed
      __syncthreads();
      cur ^= 1;
    }
  }
#undef STAGE2

  if (z < 2) {
    bf16* Cz = C + (long)z * ROWS * 512;
    #pragma unroll
    for (int mi = 0; mi < 4; ++mi) {
      #pragma unroll
      for (int ni = 0; ni < 4; ++ni) {
        const int ncf = bnf + wn + ni * 16 + (lane & 15);
        const int nc  = ncf & 511;
        const float bv = bias[ncf];
        #pragma unroll
        for (int r = 0; r < 4; ++r) {
          const long m = bm + wm + mi * 16 + (lane >> 4) * 4 + r;
          Cz[m * 512 + nc] = __float2bfloat16(acc[mi][ni][r] + bv);
        }
      }
    }
  } else {
    // v transposed per batch: vT[b][nc][j], j = m & 15; 4 r-values -> one 8B store
    ushort* vt = (ushort*)C + (long)2 * ROWS * 512;
    #pragma unroll
    for (int mi = 0; mi < 4; ++mi) {
      const int m0 = bm + wm + mi * 16;
      const long bb = (long)(m0 >> 4) * 8192;     // batch * 512 * 16
      #pragma unroll
      for (int ni = 0; ni < 4; ++ni) {
        const int ncf = bnf + wn + ni * 16 + (lane & 15);
        const int nc  = ncf & 511;
        const float bv = bias[ncf];
        float v0 = acc[mi][ni][0] + bv, v1 = acc[mi][ni][1] + bv;
        float v2 = acc[mi][ni][2] + bv, v3 = acc[mi][ni][3] + bv;
        uint2 pk;
        pk.x = (uint)f2bf(v0) | ((uint)f2bf(v1) << 16);
        pk.y = (uint)f2bf(v2) | ((uint)f2bf(v3) << 16);
        *(uint2*)(vt + bb + (long)nc * 16 + (lane >> 4) * 4) = pk;
      }
    }
  }
}

// ---------------- attention v3 (validated R7): fragments straight from L2/L3 ----------------
__global__ __launch_bounds__(256) void attn_v3(
    const bf16* __restrict__ kqv,
    const float* __restrict__ flow_mask,
    float* __restrict__ out)
{
  __shared__ ushort wn_s[4 * 16 * 40];
  __shared__ float  fm_s[16];

  const int tid  = threadIdx.x;
  const int lane = tid & 63;
  const int wave = tid >> 6;
  const int b    = blockIdx.x;

  if (tid < 16) fm_s[tid] = flow_mask[tid];
  __syncthreads();

  const int jcol = lane & 15;
  const int rgrp = lane >> 4;
  const int ko   = rgrp * 8;

  {
    const bf16* kg = kqv + ((long)b * 16 + jcol) * 512;
    const bf16* qg = kg + 16777216;
    const float fmj = fm_s[jcol];
    #pragma unroll
    for (int h = 0; h < 2; ++h) {
      const int c = wave + h * 4;
      floatx4 acc = {0.f, 0.f, 0.f, 0.f};
      bf16x8 a0 = *(const bf16x8*)(kg + c * 64 + ko);
      bf16x8 a1 = *(const bf16x8*)(kg + c * 64 + 32 + ko);
      bf16x8 b0 = *(const bf16x8*)(qg + c * 64 + ko);
      bf16x8 b1 = *(const bf16x8*)(qg + c * 64 + 32 + ko);
      acc = MFMA(a0, b0, acc);
      acc = MFMA(a1, b1, acc);

      float wv[4], ss[4];
      #pragma unroll
      for (int r = 0; r < 4; ++r) {
        const int i = rgrp * 4 + r;
        float arg = acc[r] * (fm_s[i] * fmj * 0.125f);
        float sp  = fmaxf(arg, 0.f) + log1pf(__expf(-fabsf(arg)));
        float wvv = sp + 1e-5f;
        if (i == jcol) wvv = 0.f;      // mask_self
        wv[r] = wvv; ss[r] = wvv;
      }
      #pragma unroll
      for (int m = 1; m < 16; m <<= 1) {
        #pragma unroll
        for (int r = 0; r < 4; ++r) ss[r] += __shfl_xor(ss[r], m);
      }
      const int hp = c >> 1, chl = c & 1;
      #pragma unroll
      for (int r = 0; r < 4; ++r) {
        const int i = rgrp * 4 + r;
        wn_s[hp * 640 + i * 40 + chl * 16 + jcol] = f2bf(wv[r] / ss[r] * fmj);
      }
    }
  }
  __syncthreads();

  {
    const int dcol = wave * 16 + jcol;
    const ushort* vb = (const ushort*)kqv + (long)2 * ROWS * 512 + (long)b * 8192;
    floatx4 o = {0.f, 0.f, 0.f, 0.f};
    #pragma unroll
    for (int hp = 0; hp < 4; ++hp) {
      bf16x8 af = *(const bf16x8*)&wn_s[hp * 640 + jcol * 40 + ko];
      const int c  = 2 * hp + (ko >> 4);
      const int jb = ko & 15;
      bf16x8 bfr = *(const bf16x8*)(vb + (long)(c * 64 + dcol) * 16 + jb);
      o = MFMA(af, bfr, o);
    }
    float* ob = out + (long)b * 1024 + dcol;
    #pragma unroll
    for (int r = 0; r < 4; ++r) ob[(rgrp * 4 + r) * 64] = o[r];
  }
}

// ---------------- launch ----------------
extern "C" void kernel_launch(void* const* d_in, const int* in_sizes, int n_in,
                              void* d_out, int out_size, void* d_ws, size_t ws_size,
                              hipStream_t stream) {
  const float* x    = (const float*)d_in[0];
  const float* fmk  = (const float*)d_in[1];
  const float* Wk_h = (const float*)d_in[2];
  const float* bk_h = (const float*)d_in[3];
  const float* Wk_o = (const float*)d_in[4];
  const float* bk_o = (const float*)d_in[5];
  const float* Wq_h = (const float*)d_in[6];
  const float* bq_h = (const float*)d_in[7];
  const float* Wq_o = (const float*)d_in[8];
  const float* bq_o = (const float*)d_in[9];
  const float* Wv_h = (const float*)d_in[10];
  const float* bv_h = (const float*)d_in[11];
  const float* Wv_o = (const float*)d_in[12];
  const float* bv_o = (const float*)d_in[13];
  const float* pos  = (const float*)d_in[14];
  float* out = (float*)d_out;

  // workspace layout (bytes)
  char* ws = (char*)d_ws;
  bf16*  xe  = (bf16*)(ws + 0);           //   6,291,456 (32768 x 96)
  bf16*  w1t = (bf16*)(ws + 6291456);     //     294,912 (1536 x 96)
  bf16*  w2t = (bf16*)(ws + 6586368);     //   1,572,864 (1536 x 512)
  float* b1  = (float*)(ws + 8159232);    //       6,144
  float* b2  = (float*)(ws + 8165376);    //       6,144
  bf16*  hid = (bf16*)(ws + 8171520);     // 100,663,296 (32768 x 1536)
  bf16*  kqv = (bf16*)(ws + 108834816);   // 100,663,296 (k | q | vT)
  if (ws_size < 209498112ULL) return;

  prep_misc<<<12300, 256, 0, stream>>>(x, pos, bk_h, bq_h, bv_h, bk_o, bq_o, bv_o,
                                       xe, b1, b2);
  prep_wt<<<912, 256, 0, stream>>>(Wk_h, Wq_h, Wv_h, Wk_o, Wq_o, Wv_o, w1t, w2t);
  gemm1_reg<<<dim3(512, 6), 256, 0, stream>>>(xe, w1t, b1, hid);
  mlp_gemm2<<<dim3(256, 12), 256, 0, stream>>>(hid, w2t, b2, kqv);
  attn_v3<<<2048, 256, 0, stream>>>(kqv, fmk, out);
}

// Round 10
// 231.255 us; speedup vs baseline: 1.1345x; 1.1345x over previous
//
#include <hip/hip_runtime.h>
#include <hip/hip_bf16.h>

typedef __hip_bfloat16 bf16;
typedef __attribute__((ext_vector_type(8))) short bf16x8;
typedef __attribute__((ext_vector_type(4))) float floatx4;
typedef unsigned short ushort;
typedef unsigned int uint;

#define ROWS 32768
#define KX 96          // padded d_ext (70 -> 96)

#define MFMA(a, b, c) __builtin_amdgcn_mfma_f32_16x16x32_bf16(a, b, c, 0, 0, 0)
#define GL_LDS(gp, lp) __builtin_amdgcn_global_load_lds( \
    (const __attribute__((address_space(1))) unsigned int*)(gp), \
    (__attribute__((address_space(3))) unsigned int*)(lp), 16, 0, 0)

__device__ __forceinline__ ushort f2bf(float f) {
  union { float f; unsigned int i; } u; u.f = f;
  return (ushort)((u.i + 0x7fffu + ((u.i >> 16) & 1u)) >> 16);   // RNE
}

// ---------------- prep: xe (32768 x 96 bf16) + biases ----------------
__global__ void prep_misc(const float* __restrict__ x, const float* __restrict__ pos,
    const float* __restrict__ bk1, const float* __restrict__ bq1, const float* __restrict__ bv1,
    const float* __restrict__ bk2, const float* __restrict__ bq2, const float* __restrict__ bv2,
    bf16* __restrict__ xe, float* __restrict__ b1, float* __restrict__ b2)
{
  int idx = blockIdx.x * 256 + threadIdx.x;
  if (idx < ROWS * KX) {
    int r = idx / KX, col = idx - r * KX;
    float v = 0.f;
    if (col < 64)      v = x[r * 64 + col];
    else if (col < 70) v = pos[(r & 15) * 6 + (col - 64)];
    xe[idx] = __float2bfloat16(v);
  } else if (idx < ROWS * KX + 3072) {
    int i = idx - ROWS * KX;
    if (i < 1536) {
      int z = i >> 9, nl = i & 511;
      const float* s = (z == 0) ? bk1 : (z == 1) ? bq1 : bv1;
      b1[i] = s[nl];
    } else {
      int j = i - 1536;
      int z = j >> 9, nl = j & 511;
      const float* s = (z == 0) ? bk2 : (z == 1) ? bq2 : bv2;
      b2[j] = s[nl];
    }
  }
}

// ---------------- prep: tiled transpose W1 (70x512 -> [z*512+n]x96), W2 (512x512 -> n,k) ----------------
__global__ __launch_bounds__(256) void prep_wt(
    const float* __restrict__ Wk_h, const float* __restrict__ Wq_h, const float* __restrict__ Wv_h,
    const float* __restrict__ Wk_o, const float* __restrict__ Wq_o, const float* __restrict__ Wv_o,
    bf16* __restrict__ w1t, bf16* __restrict__ w2t)
{
  __shared__ float tile[32][33];
  const int bid = blockIdx.x;
  const int c = threadIdx.x & 31, r0 = threadIdx.x >> 5;
  if (bid < 768) {            // W2: z x nt(16) x kt(16)
    const int z = bid >> 8, rem = bid & 255;
    const int nt = rem >> 4, kt = rem & 15;
    const float* src = (z == 0) ? Wk_o : (z == 1) ? Wq_o : Wv_o;
    #pragma unroll
    for (int rr = 0; rr < 4; ++rr) {
      int r = r0 + rr * 8;
      tile[r][c] = src[(kt * 32 + r) * 512 + nt * 32 + c];
    }
    __syncthreads();
    #pragma unroll
    for (int rr = 0; rr < 4; ++rr) {
      int r = r0 + rr * 8;
      w2t[((long)z * 512 + nt * 32 + r) * 512 + kt * 32 + c] = __float2bfloat16(tile[c][r]);
    }
  } else {                    // W1: z(3) x kt(3) x nt(16)
    const int b2i = bid - 768;
    const int z = b2i / 48, rem = b2i - z * 48;
    const int kt = rem >> 4, nt = rem & 15;
    const float* src = (z == 0) ? Wk_h : (z == 1) ? Wq_h : Wv_h;
    #pragma unroll
    for (int rr = 0; rr < 4; ++rr) {
      int r = r0 + rr * 8;
      int k = kt * 32 + r;
      tile[r][c] = (k < 70) ? src[k * 512 + nt * 32 + c] : 0.f;
    }
    __syncthreads();
    #pragma unroll
    for (int rr = 0; rr < 4; ++rr) {
      int r = r0 + rr * 8;
      w1t[((long)z * 512 + nt * 32 + r) * KX + kt * 32 + c] = __float2bfloat16(tile[c][r]);
    }
  }
}

// ---------------- GEMM1: 128x128, K=96 fully prefetched (3 stages), counted vmcnt ----------------
// grid (256, 12): bm = x*128, flat n = y*128. Block eats HBM latency ONCE, not per K-step.
__global__ __launch_bounds__(256) void gemm1_pf(
    const bf16* __restrict__ xe, const bf16* __restrict__ w1t,
    const float* __restrict__ bias, bf16* __restrict__ hid)
{
  __shared__ __align__(16) bf16 As[3][128 * 32];
  __shared__ __align__(16) bf16 Bs[3][128 * 32];
  const int tid  = threadIdx.x;
  const int wave = tid >> 6, lane = tid & 63;
  const int bm  = blockIdx.x * 128;
  const int bnf = blockIdx.y * 128;
  const int wm = (wave >> 1) * 64;
  const int wn = (wave & 1) * 64;
  const int arow = lane >> 2;
  const int acol = (lane & 3) * 8;

  // issue ALL staging loads up front (12 gl_lds/thread in flight)
  #pragma unroll
  for (int s = 0; s < 3; ++s) {
    const int k0 = s * 32;
    #pragma unroll
    for (int ch = 0; ch < 2; ++ch) {
      const int rb = wave * 32 + ch * 16;
      GL_LDS(xe  + (long)(bm  + rb + arow) * KX + k0 + acol, As[s] + rb * 32);
      GL_LDS(w1t + (long)(bnf + rb + arow) * KX + k0 + acol, Bs[s] + rb * 32);
    }
  }

  floatx4 acc[4][4] = {};
  #pragma unroll
  for (int s = 0; s < 3; ++s) {
    if (s == 0)      asm volatile("s_waitcnt vmcnt(8)\n\ts_barrier" ::: "memory");
    else if (s == 1) asm volatile("s_waitcnt vmcnt(4)\n\ts_barrier" ::: "memory");
    else             asm volatile("s_waitcnt vmcnt(0)\n\ts_barrier" ::: "memory");
    bf16x8 af[4], bfr[4];
    #pragma unroll
    for (int mi = 0; mi < 4; ++mi)
      af[mi] = *(const bf16x8*)(As[s] + (wm + mi * 16 + (lane & 15)) * 32 + (lane >> 4) * 8);
    #pragma unroll
    for (int ni = 0; ni < 4; ++ni)
      bfr[ni] = *(const bf16x8*)(Bs[s] + (wn + ni * 16 + (lane & 15)) * 32 + (lane >> 4) * 8);
    #pragma unroll
    for (int mi = 0; mi < 4; ++mi)
      #pragma unroll
      for (int ni = 0; ni < 4; ++ni)
        acc[mi][ni] = MFMA(af[mi], bfr[ni], acc[mi][ni]);
  }

  // epilogue: bias + silu -> hid (ldc = 1536)
  #pragma unroll
  for (int mi = 0; mi < 4; ++mi) {
    #pragma unroll
    for (int ni = 0; ni < 4; ++ni) {
      const int nc = bnf + wn + ni * 16 + (lane & 15);
      const float bv = bias[nc];
      #pragma unroll
      for (int r = 0; r < 4; ++r) {
        const long m = bm + wm + mi * 16 + (lane >> 4) * 4 + r;
        float v = acc[mi][ni][r] + bv;
        v = v / (1.f + __expf(-v));            // silu
        hid[m * 1536 + nc] = __float2bfloat16(v);
      }
    }
  }
}

// ---------------- GEMM2: 128x128, BK=32, 4 buffers, 3-deep counted-vmcnt pipeline ----------------
// grid (256, 12): y -> (z = y>>2, nb = y&3). K=512 (16 K-steps). One barrier per step.
// Epilogue: z<2 -> kqv rows; z==2 -> vT[b][col][j] packed (for attn PV).
__global__ __launch_bounds__(256) void gemm2_cnt(
    const bf16* __restrict__ A,            // hid, lda = 1536 (col offset z*512)
    const bf16* __restrict__ Bt,           // w2t [1536][512]
    const float* __restrict__ bias,        // flat 1536
    bf16* __restrict__ C)                  // kqv base (k | q | vT)
{
  __shared__ __align__(16) bf16 As[4][128 * 32];
  __shared__ __align__(16) bf16 Bs[4][128 * 32];
  const int tid  = threadIdx.x;
  const int wave = tid >> 6, lane = tid & 63;
  const int z  = blockIdx.y >> 2;
  const int bn = (blockIdx.y & 3) * 128;         // within z
  const int bm = blockIdx.x * 128;
  const int bnf = z * 512 + bn;                  // flat n
  const bf16* Ap  = A + z * 512;
  const bf16* Btp = Bt + (long)z * 512 * 512;
  const int wm = (wave >> 1) * 64;
  const int wn = (wave & 1) * 64;
  const int arow = lane >> 2;
  const int acol = (lane & 3) * 8;

#define STAGE2(buf, t) do {                                                        \
    const int k0_ = (t) * 32;                                                      \
    _Pragma("unroll")                                                              \
    for (int ch = 0; ch < 2; ++ch) {                                               \
      const int rb = wave * 32 + ch * 16;                                          \
      GL_LDS(Ap  + (long)(bm + rb + arow) * 1536 + k0_ + acol, As[buf] + rb * 32); \
      GL_LDS(Btp + (long)(bn + rb + arow) * 512  + k0_ + acol, Bs[buf] + rb * 32); \
    } } while (0)

  STAGE2(0, 0);
  STAGE2(1, 1);
  STAGE2(2, 2);          // 12 loads/thread in flight

  floatx4 acc[4][4] = {};
  for (int t = 0; t < 16; ++t) {
    // counted wait: tile t landed; tiles t+1, t+2 stay in flight (never drain mid-loop)
    if (t <= 13)      asm volatile("s_waitcnt vmcnt(8)\n\ts_barrier" ::: "memory");
    else if (t == 14) asm volatile("s_waitcnt vmcnt(4)\n\ts_barrier" ::: "memory");
    else              asm volatile("s_waitcnt vmcnt(0)\n\ts_barrier" ::: "memory");
    // stage-early: buffer (t+3)&3 was freed by the barrier above (last read at t-1)
    if (t + 3 < 16) STAGE2((t + 3) & 3, t + 3);

    const bf16* Ab = As[t & 3];
    const bf16* Bb = Bs[t & 3];
    bf16x8 af[4], bfr[4];
    #pragma unroll
    for (int mi = 0; mi < 4; ++mi)
      af[mi] = *(const bf16x8*)(Ab + (wm + mi * 16 + (lane & 15)) * 32 + (lane >> 4) * 8);
    #pragma unroll
    for (int ni = 0; ni < 4; ++ni)
      bfr[ni] = *(const bf16x8*)(Bb + (wn + ni * 16 + (lane & 15)) * 32 + (lane >> 4) * 8);
    #pragma unroll
    for (int mi = 0; mi < 4; ++mi)
      #pragma unroll
      for (int ni = 0; ni < 4; ++ni)
        acc[mi][ni] = MFMA(af[mi], bfr[ni], acc[mi][ni]);
  }
#undef STAGE2

  if (z < 2) {
    bf16* Cz = C + (long)z * ROWS * 512;
    #pragma unroll
    for (int mi = 0; mi < 4; ++mi) {
      #pragma unroll
      for (int ni = 0; ni < 4; ++ni) {
        const int ncf = bnf + wn + ni * 16 + (lane & 15);
        const int nc  = ncf & 511;
        const float bv = bias[ncf];
        #pragma unroll
        for (int r = 0; r < 4; ++r) {
          const long m = bm + wm + mi * 16 + (lane >> 4) * 4 + r;
          Cz[m * 512 + nc] = __float2bfloat16(acc[mi][ni][r] + bv);
        }
      }
    }
  } else {
    // v transposed per batch: vT[b][nc][j], j = m & 15; 4 r-values -> one 8B store
    ushort* vt = (ushort*)C + (long)2 * ROWS * 512;
    #pragma unroll
    for (int mi = 0; mi < 4; ++mi) {
      const int m0 = bm + wm + mi * 16;
      const long bb = (long)(m0 >> 4) * 8192;     // batch * 512 * 16
      #pragma unroll
      for (int ni = 0; ni < 4; ++ni) {
        const int ncf = bnf + wn + ni * 16 + (lane & 15);
        const int nc  = ncf & 511;
        const float bv = bias[ncf];
        float v0 = acc[mi][ni][0] + bv, v1 = acc[mi][ni][1] + bv;
        float v2 = acc[mi][ni][2] + bv, v3 = acc[mi][ni][3] + bv;
        uint2 pk;
        pk.x = (uint)f2bf(v0) | ((uint)f2bf(v1) << 16);
        pk.y = (uint)f2bf(v2) | ((uint)f2bf(v3) << 16);
        *(uint2*)(vt + bb + (long)nc * 16 + (lane >> 4) * 4) = pk;
      }
    }
  }
}

// ---------------- attention v3 (validated R7/R8): fragments straight from L2/L3 ----------------
__global__ __launch_bounds__(256) void attn_v3(
    const bf16* __restrict__ kqv,
    const float* __restrict__ flow_mask,
    float* __restrict__ out)
{
  __shared__ ushort wn_s[4 * 16 * 40];
  __shared__ float  fm_s[16];

  const int tid  = threadIdx.x;
  const int lane = tid & 63;
  const int wave = tid >> 6;
  const int b    = blockIdx.x;

  if (tid < 16) fm_s[tid] = flow_mask[tid];
  __syncthreads();

  const int jcol = lane & 15;
  const int rgrp = lane >> 4;
  const int ko   = rgrp * 8;

  {
    const bf16* kg = kqv + ((long)b * 16 + jcol) * 512;
    const bf16* qg = kg + 16777216;
    const float fmj = fm_s[jcol];
    #pragma unroll
    for (int h = 0; h < 2; ++h) {
      const int c = wave + h * 4;
      floatx4 acc = {0.f, 0.f, 0.f, 0.f};
      bf16x8 a0 = *(const bf16x8*)(kg + c * 64 + ko);
      bf16x8 a1 = *(const bf16x8*)(kg + c * 64 + 32 + ko);
      bf16x8 b0 = *(const bf16x8*)(qg + c * 64 + ko);
      bf16x8 b1 = *(const bf16x8*)(qg + c * 64 + 32 + ko);
      acc = MFMA(a0, b0, acc);
      acc = MFMA(a1, b1, acc);

      float wv[4], ss[4];
      #pragma unroll
      for (int r = 0; r < 4; ++r) {
        const int i = rgrp * 4 + r;
        float arg = acc[r] * (fm_s[i] * fmj * 0.125f);
        float sp  = fmaxf(arg, 0.f) + log1pf(__expf(-fabsf(arg)));
        float wvv = sp + 1e-5f;
        if (i == jcol) wvv = 0.f;      // mask_self
        wv[r] = wvv; ss[r] = wvv;
      }
      #pragma unroll
      for (int m = 1; m < 16; m <<= 1) {
        #pragma unroll
        for (int r = 0; r < 4; ++r) ss[r] += __shfl_xor(ss[r], m);
      }
      const int hp = c >> 1, chl = c & 1;
      #pragma unroll
      for (int r = 0; r < 4; ++r) {
        const int i = rgrp * 4 + r;
        wn_s[hp * 640 + i * 40 + chl * 16 + jcol] = f2bf(wv[r] / ss[r] * fmj);
      }
    }
  }
  __syncthreads();

  {
    const int dcol = wave * 16 + jcol;
    const ushort* vb = (const ushort*)kqv + (long)2 * ROWS * 512 + (long)b * 8192;
    floatx4 o = {0.f, 0.f, 0.f, 0.f};
    #pragma unroll
    for (int hp = 0; hp < 4; ++hp) {
      bf16x8 af = *(const bf16x8*)&wn_s[hp * 640 + jcol * 40 + ko];
      const int c  = 2 * hp + (ko >> 4);
      const int jb = ko & 15;
      bf16x8 bfr = *(const bf16x8*)(vb + (long)(c * 64 + dcol) * 16 + jb);
      o = MFMA(af, bfr, o);
    }
    float* ob = out + (long)b * 1024 + dcol;
    #pragma unroll
    for (int r = 0; r < 4; ++r) ob[(rgrp * 4 + r) * 64] = o[r];
  }
}

// ---------------- launch ----------------
extern "C" void kernel_launch(void* const* d_in, const int* in_sizes, int n_in,
                              void* d_out, int out_size, void* d_ws, size_t ws_size,
                              hipStream_t stream) {
  const float* x    = (const float*)d_in[0];
  const float* fmk  = (const float*)d_in[1];
  const float* Wk_h = (const float*)d_in[2];
  const float* bk_h = (const float*)d_in[3];
  const float* Wk_o = (const float*)d_in[4];
  const float* bk_o = (const float*)d_in[5];
  const float* Wq_h = (const float*)d_in[6];
  const float* bq_h = (const float*)d_in[7];
  const float* Wq_o = (const float*)d_in[8];
  const float* bq_o = (const float*)d_in[9];
  const float* Wv_h = (const float*)d_in[10];
  const float* bv_h = (const float*)d_in[11];
  const float* Wv_o = (const float*)d_in[12];
  const float* bv_o = (const float*)d_in[13];
  const float* pos  = (const float*)d_in[14];
  float* out = (float*)d_out;

  // workspace layout (bytes)
  char* ws = (char*)d_ws;
  bf16*  xe  = (bf16*)(ws + 0);           //   6,291,456 (32768 x 96)
  bf16*  w1t = (bf16*)(ws + 6291456);     //     294,912 (1536 x 96)
  bf16*  w2t = (bf16*)(ws + 6586368);     //   1,572,864 (1536 x 512)
  float* b1  = (float*)(ws + 8159232);    //       6,144
  float* b2  = (float*)(ws + 8165376);    //       6,144
  bf16*  hid = (bf16*)(ws + 8171520);     // 100,663,296 (32768 x 1536)
  bf16*  kqv = (bf16*)(ws + 108834816);   // 100,663,296 (k | q | vT)
  if (ws_size < 209498112ULL) return;

  prep_misc<<<12300, 256, 0, stream>>>(x, pos, bk_h, bq_h, bv_h, bk_o, bq_o, bv_o,
                                       xe, b1, b2);
  prep_wt<<<912, 256, 0, stream>>>(Wk_h, Wq_h, Wv_h, Wk_o, Wq_o, Wv_o, w1t, w2t);
  gemm1_pf<<<dim3(256, 12), 256, 0, stream>>>(xe, w1t, b1, hid);
  gemm2_cnt<<<dim3(256, 12), 256, 0, stream>>>(hid, w2t, b2, kqv);
  attn_v3<<<2048, 256, 0, stream>>>(kqv, fmk, out);
}